// Round 1
// baseline (1121.608 us; speedup 1.0000x reference)
//
#include <hip/hip_runtime.h>

#define FDIM 64
#define EPS 1e-5f

// ---------------- degree computation ----------------
__global__ void k_deg(const int* __restrict__ src, const int* __restrict__ dst,
                      float* __restrict__ degO, float* __restrict__ degI, int E) {
    int i = blockIdx.x * blockDim.x + threadIdx.x;
    if (i < E) {
        atomicAdd(&degO[src[i]], 1.0f);
        atomicAdd(&degI[dst[i]], 1.0f);
    }
}

// ---------------- bufA = x * rsqrt(max(degO,1)) ----------------
__global__ void k_scalex(const float4* __restrict__ x, const float* __restrict__ degO,
                         float4* __restrict__ out, int n4) {
    int i = blockIdx.x * blockDim.x + threadIdx.x;
    if (i < n4) {
        int n = i >> 4;  // 16 float4 per node (64 floats)
        float rs = rsqrtf(fmaxf(degO[n], 1.0f));
        float4 v = x[i];
        v.x *= rs; v.y *= rs; v.z *= rs; v.w *= rs;
        out[i] = v;
    }
}

// ---------------- SpMM scatter: out[dst] += in[src], 64 feats ----------------
__global__ void k_spmm(const float* __restrict__ hin, const int* __restrict__ src,
                       const int* __restrict__ dst, float* __restrict__ out, int E) {
    long long i = (long long)blockIdx.x * blockDim.x + threadIdx.x;
    long long total = (long long)E * FDIM;
    if (i < total) {
        int e = (int)(i >> 6);
        int f = (int)(i & 63);
        int s = src[e];
        int d = dst[e];
        atomicAdd(&out[(long long)d * FDIM + f], hin[(long long)s * FDIM + f]);
    }
}

// ---------------- GEMM (N,64)x(64,64) + deg_in scale + bias + BN stats ----------------
__global__ void k_gemm_stats(const float* __restrict__ m, const float* __restrict__ degI,
                             const float* __restrict__ W, const float* __restrict__ b,
                             float* __restrict__ out, float* __restrict__ ssum,
                             float* __restrict__ ssq, int N) {
    __shared__ float Ws[FDIM * FDIM];
    __shared__ float ms[4 * FDIM];
    __shared__ float red[256];
    int tid = threadIdx.x;
    for (int i = tid; i < FDIM * FDIM; i += 256) Ws[i] = W[i];
    int j  = tid & 63;   // channel
    int nl = tid >> 6;   // node lane 0..3
    float bj = b[j];
    float lsum = 0.f, lsq = 0.f;
    int nchunks = (N + 3) >> 2;
    for (int chunk = blockIdx.x; chunk < nchunks; chunk += gridDim.x) {
        int n = (chunk << 2) + nl;
        __syncthreads();
        ms[tid] = (n < N) ? m[(long long)n * FDIM + j] : 0.f;
        __syncthreads();
        if (n < N) {
            float acc = 0.f;
#pragma unroll
            for (int k = 0; k < FDIM; ++k)
                acc += ms[nl * FDIM + k] * Ws[k * FDIM + j];
            float rs = rsqrtf(fmaxf(degI[n], 1.0f));
            float h = acc * rs + bj;
            out[(long long)n * FDIM + j] = h;
            lsum += h;
            lsq += h * h;
        }
    }
    __syncthreads();
    red[tid] = lsum;
    __syncthreads();
    if (nl == 0) atomicAdd(&ssum[j], red[j] + red[64 + j] + red[128 + j] + red[192 + j]);
    __syncthreads();
    red[tid] = lsq;
    __syncthreads();
    if (nl == 0) atomicAdd(&ssq[j], red[j] + red[64 + j] + red[128 + j] + red[192 + j]);
}

// ---------------- finalize BN params: mu, coef = rsqrt(var+eps)*g ----------------
__global__ void k_finalize(const float* __restrict__ ssum, const float* __restrict__ ssq,
                           const float* __restrict__ g, float* __restrict__ mu,
                           float* __restrict__ coef, int N) {
    int j = threadIdx.x;
    float m = ssum[j] / (float)N;
    float v = ssq[j] / (float)N - m * m;
    mu[j] = m;
    coef[j] = rsqrtf(v + EPS) * g[j];
}

// ---------------- out = relu((h-mu)*coef+be) * rsqrt(max(degO,1)) ----------------
__global__ void k_bnrelu_scale(const float4* __restrict__ h, const float* __restrict__ mu,
                               const float* __restrict__ coef, const float* __restrict__ be,
                               const float* __restrict__ degO, float4* __restrict__ out, int n4) {
    int i = blockIdx.x * blockDim.x + threadIdx.x;
    if (i < n4) {
        int n = i >> 4;
        int j4 = (i & 15) << 2;
        float rs = rsqrtf(fmaxf(degO[n], 1.0f));
        float4 v = h[i];
        v.x = fmaxf((v.x - mu[j4 + 0]) * coef[j4 + 0] + be[j4 + 0], 0.f) * rs;
        v.y = fmaxf((v.y - mu[j4 + 1]) * coef[j4 + 1] + be[j4 + 1], 0.f) * rs;
        v.z = fmaxf((v.z - mu[j4 + 2]) * coef[j4 + 2] + be[j4 + 2], 0.f) * rs;
        v.w = fmaxf((v.w - mu[j4 + 3]) * coef[j4 + 3] + be[j4 + 3], 0.f) * rs;
        out[i] = v;
    }
}

// ---------------- relu(bn(h)) channel-sum over nodes ----------------
__global__ void k_bnrelu_mean(const float* __restrict__ h, const float* __restrict__ mu,
                              const float* __restrict__ coef, const float* __restrict__ be,
                              float* __restrict__ hsum, int N) {
    __shared__ float red[256];
    int tid = threadIdx.x;
    int j  = tid & 63;
    int nl = tid >> 6;
    float muj = mu[j], cj = coef[j], bj = be[j];
    float ls = 0.f;
    int nchunks = (N + 3) >> 2;
    for (int chunk = blockIdx.x; chunk < nchunks; chunk += gridDim.x) {
        int n = (chunk << 2) + nl;
        if (n < N) {
            float v = fmaxf((h[(long long)n * FDIM + j] - muj) * cj + bj, 0.f);
            ls += v;
        }
    }
    red[tid] = ls;
    __syncthreads();
    if (nl == 0) atomicAdd(&hsum[j], red[j] + red[64 + j] + red[128 + j] + red[192 + j]);
}

// ---------------- classifier: out = (hsum/N) @ Wc + bc ----------------
__global__ void k_final(const float* __restrict__ hsum, const float* __restrict__ Wc,
                        const float* __restrict__ bc, float* __restrict__ out, int N) {
    __shared__ float red[128];
    int j = threadIdx.x;  // 64 threads
    float hg = hsum[j] / (float)N;
    red[j]      = hg * Wc[j * 2 + 0];
    red[64 + j] = hg * Wc[j * 2 + 1];
    __syncthreads();
    if (j == 0) {
        float a = 0.f, b = 0.f;
        for (int k = 0; k < 64; ++k) { a += red[k]; b += red[64 + k]; }
        out[0] = a + bc[0];
        out[1] = b + bc[1];
    }
}

extern "C" void kernel_launch(void* const* d_in, const int* in_sizes, int n_in,
                              void* d_out, int out_size, void* d_ws, size_t ws_size,
                              hipStream_t stream) {
    const float* x   = (const float*)d_in[0];
    const int*   src = (const int*)d_in[1];
    const int*   dst = (const int*)d_in[2];
    const float* W1  = (const float*)d_in[3];
    const float* b1  = (const float*)d_in[4];
    const float* g1  = (const float*)d_in[5];
    const float* be1 = (const float*)d_in[6];
    const float* W2  = (const float*)d_in[7];
    const float* b2  = (const float*)d_in[8];
    const float* g2  = (const float*)d_in[9];
    const float* be2 = (const float*)d_in[10];
    const float* Wc  = (const float*)d_in[11];
    const float* bc  = (const float*)d_in[12];
    float* out = (float*)d_out;

    const int N = in_sizes[0] / FDIM;   // 100000
    const int E = in_sizes[1];          // 1600000

    // workspace layout (floats)
    float* w     = (float*)d_ws;
    float* degO  = w;                 // N
    float* degI  = w + N;             // N
    float* stats = w + 2 * N;         // 1024 floats of stats space
    float* sum1  = stats + 0;
    float* sq1   = stats + 64;
    float* mu1   = stats + 128;
    float* coef1 = stats + 192;
    float* sum2  = stats + 256;
    float* sq2   = stats + 320;
    float* mu2   = stats + 384;
    float* coef2 = stats + 448;
    float* hsum  = stats + 512;
    float* bufA  = w + 2 * N + 1024;        // N*64
    float* bufB  = bufA + (size_t)N * FDIM; // N*64

    const int n4 = N * (FDIM / 4);  // float4 count per node-feature buffer
    const long long spmm_threads = (long long)E * FDIM;
    const int spmm_blocks = (int)((spmm_threads + 255) / 256);

    // zero degrees + stats in one shot, and SpMM1 accumulator
    hipMemsetAsync(degO, 0, (size_t)(2 * N + 1024) * sizeof(float), stream);
    hipMemsetAsync(bufB, 0, (size_t)N * FDIM * sizeof(float), stream);

    k_deg<<<(E + 255) / 256, 256, 0, stream>>>(src, dst, degO, degI, E);
    k_scalex<<<(n4 + 255) / 256, 256, 0, stream>>>((const float4*)x, degO, (float4*)bufA, n4);
    k_spmm<<<spmm_blocks, 256, 0, stream>>>(bufA, src, dst, bufB, E);
    k_gemm_stats<<<1024, 256, 0, stream>>>(bufB, degI, W1, b1, bufA, sum1, sq1, N);
    k_finalize<<<1, 64, 0, stream>>>(sum1, sq1, g1, mu1, coef1, N);
    k_bnrelu_scale<<<(n4 + 255) / 256, 256, 0, stream>>>((const float4*)bufA, mu1, coef1, be1,
                                                         degO, (float4*)bufB, n4);
    hipMemsetAsync(bufA, 0, (size_t)N * FDIM * sizeof(float), stream);
    k_spmm<<<spmm_blocks, 256, 0, stream>>>(bufB, src, dst, bufA, E);
    k_gemm_stats<<<1024, 256, 0, stream>>>(bufA, degI, W2, b2, bufB, sum2, sq2, N);
    k_finalize<<<1, 64, 0, stream>>>(sum2, sq2, g2, mu2, coef2, N);
    k_bnrelu_mean<<<1024, 256, 0, stream>>>(bufB, mu2, coef2, be2, hsum, N);
    k_final<<<1, 64, 0, stream>>>(hsum, Wc, bc, out, N);
}

// Round 2
// 648.983 us; speedup vs baseline: 1.7283x; 1.7283x over previous
//
#include <hip/hip_runtime.h>

#define FDIM 64
#define EPS 1e-5f
#define SCAN_CHUNK 1024   // elements per scan block (256 threads x 4)

// ---------------- degree computation ----------------
__global__ void k_deg(const int* __restrict__ src, const int* __restrict__ dst,
                      float* __restrict__ degO, int* __restrict__ degI, int E) {
    int i = blockIdx.x * blockDim.x + threadIdx.x;
    if (i < E) {
        atomicAdd(&degO[src[i]], 1.0f);
        atomicAdd(&degI[dst[i]], 1);
    }
}

// ---------------- scan pass 1: per-block exclusive scan + block sums ----------------
__global__ void k_scan_local(const int* __restrict__ deg, int* __restrict__ rowptr,
                             int* __restrict__ blocksum, int N) {
    __shared__ int s[256];
    int tid = threadIdx.x;
    int base = blockIdx.x * SCAN_CHUNK + tid * 4;
    int v[4];
    int sum = 0;
#pragma unroll
    for (int i = 0; i < 4; ++i) {
        v[i] = sum;
        int idx = base + i;
        sum += (idx < N) ? deg[idx] : 0;
    }
    s[tid] = sum;
    __syncthreads();
    // Hillis-Steele inclusive scan over 256 thread sums
    for (int off = 1; off < 256; off <<= 1) {
        int t = (tid >= off) ? s[tid - off] : 0;
        __syncthreads();
        s[tid] += t;
        __syncthreads();
    }
    int texc = (tid > 0) ? s[tid - 1] : 0;
#pragma unroll
    for (int i = 0; i < 4; ++i) {
        int idx = base + i;
        if (idx < N) rowptr[idx] = texc + v[i];
    }
    if (tid == 255) blocksum[blockIdx.x] = s[255];
}

// ---------------- scan pass 2: exclusive scan of block sums (tiny) ----------------
__global__ void k_scan_blocks(int* __restrict__ blocksum, int nb) {
    if (threadIdx.x == 0) {
        int acc = 0;
        for (int i = 0; i < nb; ++i) { int t = blocksum[i]; blocksum[i] = acc; acc += t; }
    }
}

// ---------------- scan pass 3: add block offsets ----------------
__global__ void k_scan_add(int* __restrict__ rowptr, const int* __restrict__ blocksum,
                           int N, int E) {
    int i = blockIdx.x * blockDim.x + threadIdx.x;
    if (i < N) rowptr[i] += blocksum[i / SCAN_CHUNK];
    if (i == 0) rowptr[N] = E;
}

// ---------------- scatter edges into CSR (grouped by dst) ----------------
__global__ void k_scatter(const int* __restrict__ src, const int* __restrict__ dst,
                          const int* __restrict__ rowptr, int* __restrict__ cnt,
                          int* __restrict__ csr_src, int E) {
    int e = blockIdx.x * blockDim.x + threadIdx.x;
    if (e < E) {
        int d = dst[e];
        int pos = rowptr[d] + atomicAdd(&cnt[d], 1);
        csr_src[pos] = src[e];
    }
}

// ---------------- bufA = x * rsqrt(max(degO,1)) ----------------
__global__ void k_scalex(const float4* __restrict__ x, const float* __restrict__ degO,
                         float4* __restrict__ out, int n4) {
    int i = blockIdx.x * blockDim.x + threadIdx.x;
    if (i < n4) {
        int n = i >> 4;  // 16 float4 per node (64 floats)
        float rs = rsqrtf(fmaxf(degO[n], 1.0f));
        float4 v = x[i];
        v.x *= rs; v.y *= rs; v.z *= rs; v.w *= rs;
        out[i] = v;
    }
}

// ---------------- CSR SpMM: one wave per dst node, lane = feature ----------------
// out[n,f] = rsqrt(max(deg_in,1)) * sum_{e in row n} hin[csr_src[e], f]
__global__ void k_spmm_csr(const float* __restrict__ hin, const int* __restrict__ rowptr,
                           const int* __restrict__ csr_src, float* __restrict__ out, int N) {
    int wave = (blockIdx.x * blockDim.x + threadIdx.x) >> 6;
    int lane = threadIdx.x & 63;
    if (wave >= N) return;
    int start = rowptr[wave];
    int end   = rowptr[wave + 1];
    float a0 = 0.f, a1 = 0.f, a2 = 0.f, a3 = 0.f;
    int e = start;
    for (; e + 4 <= end; e += 4) {
        int s0 = csr_src[e];
        int s1 = csr_src[e + 1];
        int s2 = csr_src[e + 2];
        int s3 = csr_src[e + 3];
        a0 += hin[(size_t)s0 * FDIM + lane];
        a1 += hin[(size_t)s1 * FDIM + lane];
        a2 += hin[(size_t)s2 * FDIM + lane];
        a3 += hin[(size_t)s3 * FDIM + lane];
    }
    for (; e < end; ++e)
        a0 += hin[(size_t)csr_src[e] * FDIM + lane];
    float rs = rsqrtf(fmaxf((float)(end - start), 1.0f));
    out[(size_t)wave * FDIM + lane] = ((a0 + a1) + (a2 + a3)) * rs;
}

// ---------------- GEMM (N,64)x(64,64) + bias + BN stats ----------------
__global__ void k_gemm_stats(const float* __restrict__ m, const float* __restrict__ W,
                             const float* __restrict__ b, float* __restrict__ out,
                             float* __restrict__ ssum, float* __restrict__ ssq, int N) {
    __shared__ float Ws[FDIM * FDIM];
    __shared__ float ms[4 * FDIM];
    __shared__ float red[256];
    int tid = threadIdx.x;
    for (int i = tid; i < FDIM * FDIM; i += 256) Ws[i] = W[i];
    int j  = tid & 63;   // channel
    int nl = tid >> 6;   // node lane 0..3
    float bj = b[j];
    float lsum = 0.f, lsq = 0.f;
    int nchunks = (N + 3) >> 2;
    for (int chunk = blockIdx.x; chunk < nchunks; chunk += gridDim.x) {
        int n = (chunk << 2) + nl;
        __syncthreads();
        ms[tid] = (n < N) ? m[(size_t)n * FDIM + j] : 0.f;
        __syncthreads();
        if (n < N) {
            float acc = 0.f;
#pragma unroll
            for (int k = 0; k < FDIM; ++k)
                acc += ms[nl * FDIM + k] * Ws[k * FDIM + j];
            float h = acc + bj;
            out[(size_t)n * FDIM + j] = h;
            lsum += h;
            lsq += h * h;
        }
    }
    __syncthreads();
    red[tid] = lsum;
    __syncthreads();
    if (nl == 0) atomicAdd(&ssum[j], red[j] + red[64 + j] + red[128 + j] + red[192 + j]);
    __syncthreads();
    red[tid] = lsq;
    __syncthreads();
    if (nl == 0) atomicAdd(&ssq[j], red[j] + red[64 + j] + red[128 + j] + red[192 + j]);
}

// ---------------- finalize BN params: mu, coef = rsqrt(var+eps)*g ----------------
__global__ void k_finalize(const float* __restrict__ ssum, const float* __restrict__ ssq,
                           const float* __restrict__ g, float* __restrict__ mu,
                           float* __restrict__ coef, int N) {
    int j = threadIdx.x;
    float m = ssum[j] / (float)N;
    float v = ssq[j] / (float)N - m * m;
    mu[j] = m;
    coef[j] = rsqrtf(v + EPS) * g[j];
}

// ---------------- out = relu((h-mu)*coef+be) * rsqrt(max(degO,1)) ----------------
__global__ void k_bnrelu_scale(const float4* __restrict__ h, const float* __restrict__ mu,
                               const float* __restrict__ coef, const float* __restrict__ be,
                               const float* __restrict__ degO, float4* __restrict__ out, int n4) {
    int i = blockIdx.x * blockDim.x + threadIdx.x;
    if (i < n4) {
        int n = i >> 4;
        int j4 = (i & 15) << 2;
        float rs = rsqrtf(fmaxf(degO[n], 1.0f));
        float4 v = h[i];
        v.x = fmaxf((v.x - mu[j4 + 0]) * coef[j4 + 0] + be[j4 + 0], 0.f) * rs;
        v.y = fmaxf((v.y - mu[j4 + 1]) * coef[j4 + 1] + be[j4 + 1], 0.f) * rs;
        v.z = fmaxf((v.z - mu[j4 + 2]) * coef[j4 + 2] + be[j4 + 2], 0.f) * rs;
        v.w = fmaxf((v.w - mu[j4 + 3]) * coef[j4 + 3] + be[j4 + 3], 0.f) * rs;
        out[i] = v;
    }
}

// ---------------- relu(bn(h)) channel-sum over nodes ----------------
__global__ void k_bnrelu_mean(const float* __restrict__ h, const float* __restrict__ mu,
                              const float* __restrict__ coef, const float* __restrict__ be,
                              float* __restrict__ hsum, int N) {
    __shared__ float red[256];
    int tid = threadIdx.x;
    int j  = tid & 63;
    int nl = tid >> 6;
    float muj = mu[j], cj = coef[j], bj = be[j];
    float ls = 0.f;
    int nchunks = (N + 3) >> 2;
    for (int chunk = blockIdx.x; chunk < nchunks; chunk += gridDim.x) {
        int n = (chunk << 2) + nl;
        if (n < N) {
            float v = fmaxf((h[(size_t)n * FDIM + j] - muj) * cj + bj, 0.f);
            ls += v;
        }
    }
    red[tid] = ls;
    __syncthreads();
    if (nl == 0) atomicAdd(&hsum[j], red[j] + red[64 + j] + red[128 + j] + red[192 + j]);
}

// ---------------- classifier: out = (hsum/N) @ Wc + bc ----------------
__global__ void k_final(const float* __restrict__ hsum, const float* __restrict__ Wc,
                        const float* __restrict__ bc, float* __restrict__ out, int N) {
    __shared__ float red[128];
    int j = threadIdx.x;  // 64 threads
    float hg = hsum[j] / (float)N;
    red[j]      = hg * Wc[j * 2 + 0];
    red[64 + j] = hg * Wc[j * 2 + 1];
    __syncthreads();
    if (j == 0) {
        float a = 0.f, b = 0.f;
        for (int k = 0; k < 64; ++k) { a += red[k]; b += red[64 + k]; }
        out[0] = a + bc[0];
        out[1] = b + bc[1];
    }
}

extern "C" void kernel_launch(void* const* d_in, const int* in_sizes, int n_in,
                              void* d_out, int out_size, void* d_ws, size_t ws_size,
                              hipStream_t stream) {
    const float* x   = (const float*)d_in[0];
    const int*   src = (const int*)d_in[1];
    const int*   dst = (const int*)d_in[2];
    const float* W1  = (const float*)d_in[3];
    const float* b1  = (const float*)d_in[4];
    const float* g1  = (const float*)d_in[5];
    const float* be1 = (const float*)d_in[6];
    const float* W2  = (const float*)d_in[7];
    const float* b2  = (const float*)d_in[8];
    const float* g2  = (const float*)d_in[9];
    const float* be2 = (const float*)d_in[10];
    const float* Wc  = (const float*)d_in[11];
    const float* bc  = (const float*)d_in[12];
    float* out = (float*)d_out;

    const int N = in_sizes[0] / FDIM;   // 100000
    const int E = in_sizes[1];          // 1600000

    // ---- workspace layout (16B-aligned big buffers first) ----
    char* w = (char*)d_ws;
    float* bufA    = (float*)w;                                   // N*64 f
    float* bufB    = bufA + (size_t)N * FDIM;                     // N*64 f
    int*   csr_src = (int*)(bufB + (size_t)N * FDIM);             // E int
    float* degO    = (float*)(csr_src + E);                       // N f    } zeroed
    int*   degI    = (int*)(degO + N);                            // N int  } zeroed
    int*   cnt     = degI + N;                                    // N int  } zeroed
    float* stats   = (float*)(cnt + N);                           // 1024 f } zeroed
    int*   rowptr  = (int*)(stats + 1024);                        // N+1 int
    int*   blocksum= rowptr + N + 1;                              // <=128 int

    float* sum1  = stats + 0;
    float* sq1   = stats + 64;
    float* mu1   = stats + 128;
    float* coef1 = stats + 192;
    float* sum2  = stats + 256;
    float* sq2   = stats + 320;
    float* mu2   = stats + 384;
    float* coef2 = stats + 448;
    float* hsum  = stats + 512;

    const int n4 = N * (FDIM / 4);
    const int nscan = (N + SCAN_CHUNK - 1) / SCAN_CHUNK;
    const int spmm_blocks = (N * (FDIM / 4) + 63) / 64;  // N waves, 4 waves/block (256 thr)

    // zero degO, degI, cnt, stats in one memset (contiguous, 3N+1024 words)
    hipMemsetAsync(degO, 0, (size_t)(3 * N + 1024) * 4, stream);

    k_deg<<<(E + 255) / 256, 256, 0, stream>>>(src, dst, degO, degI, E);
    k_scan_local<<<nscan, 256, 0, stream>>>(degI, rowptr, blocksum, N);
    k_scan_blocks<<<1, 64, 0, stream>>>(blocksum, nscan);
    k_scan_add<<<(N + 255) / 256, 256, 0, stream>>>(rowptr, blocksum, N, E);
    k_scatter<<<(E + 255) / 256, 256, 0, stream>>>(src, dst, rowptr, cnt, csr_src, E);

    k_scalex<<<(n4 + 255) / 256, 256, 0, stream>>>((const float4*)x, degO, (float4*)bufA, n4);
    k_spmm_csr<<<spmm_blocks, 256, 0, stream>>>(bufA, rowptr, csr_src, bufB, N);
    k_gemm_stats<<<1024, 256, 0, stream>>>(bufB, W1, b1, bufA, sum1, sq1, N);
    k_finalize<<<1, 64, 0, stream>>>(sum1, sq1, g1, mu1, coef1, N);
    k_bnrelu_scale<<<(n4 + 255) / 256, 256, 0, stream>>>((const float4*)bufA, mu1, coef1, be1,
                                                         degO, (float4*)bufB, n4);
    k_spmm_csr<<<spmm_blocks, 256, 0, stream>>>(bufB, rowptr, csr_src, bufA, N);
    k_gemm_stats<<<1024, 256, 0, stream>>>(bufA, W2, b2, bufB, sum2, sq2, N);
    k_finalize<<<1, 64, 0, stream>>>(sum2, sq2, g2, mu2, coef2, N);
    k_bnrelu_mean<<<1024, 256, 0, stream>>>(bufB, mu2, coef2, be2, hsum, N);
    k_final<<<1, 64, 0, stream>>>(hsum, Wc, bc, out, N);
}